// Round 1
// baseline (111.062 us; speedup 1.0000x reference)
//
#include <hip/hip_runtime.h>
#include <hip/hip_bf16.h>

typedef short bf16x8 __attribute__((ext_vector_type(8)));
typedef float f32x4 __attribute__((ext_vector_type(4)));

#define BETA 10.0f

__device__ __forceinline__ unsigned short f2bf(float f) {
    unsigned u = __float_as_uint(f);
    u += 0x7FFFu + ((u >> 16) & 1u);   // round-to-nearest-even
    return (unsigned short)(u >> 16);
}

// Precompute: centers -> bf16 row-major [1024][64], c2[j] = ||c_j||^2
__global__ void rbfn_prep(const float* __restrict__ centers,
                          unsigned short* __restrict__ cbf,
                          float* __restrict__ c2ws) {
    const int j = blockIdx.x;      // 1024 blocks, one center row each
    const int lane = threadIdx.x;  // 64 threads = 1 wave
    float v = centers[j * 64 + lane];
    cbf[j * 64 + lane] = f2bf(v);
    float s = v * v;
    #pragma unroll
    for (int m = 1; m < 64; m <<= 1) s += __shfl_xor(s, m);
    if (lane == 0) c2ws[j] = s;
}

// Main: block = 64 rows x 1024 centers, fused rbf + both GEMMs.
// wave w owns columns [w*256, w*256+256) as 16 col-tiles of 16.
__global__ __launch_bounds__(256, 2) void rbfn_main(
    const float* __restrict__ x,
    const unsigned short* __restrict__ cbf,
    const float* __restrict__ c2ws,
    const float* __restrict__ W,
    const float* __restrict__ b,
    float* __restrict__ out)
{
    __shared__ float lds_W[3][1024];   // W_rbf columns
    __shared__ float lds_c2[1024];
    __shared__ float lds_x2p[256];
    __shared__ float lds_x2[64];
    __shared__ float red[4][64][3];    // per-wave partial outputs

    const int tid  = threadIdx.x;
    const int wave = tid >> 6;
    const int lane = tid & 63;
    const int quad = lane >> 4;
    const int l15  = lane & 15;
    const int row0 = blockIdx.x * 64;

    // stage W_rbf (3x1024) and c2 (1024), coalesced
    for (int idx = tid; idx < 3072; idx += 256) {
        int k = idx >> 10, j = idx & 1023;
        ((float*)lds_W)[idx] = W[k * 1088 + 64 + j];
    }
    for (int idx = tid; idx < 1024; idx += 256)
        lds_c2[idx] = c2ws[idx];

    // x2 per row (64 rows, 4 threads/row)
    {
        int r = tid >> 2, seg = tid & 3;
        const float* xr = x + (size_t)(row0 + r) * 64 + seg * 16;
        float s = 0.f;
        #pragma unroll
        for (int c = 0; c < 16; ++c) s += xr[c] * xr[c];
        lds_x2p[tid] = s;
    }
    __syncthreads();
    if (tid < 64)
        lds_x2[tid] = lds_x2p[tid * 4] + lds_x2p[tid * 4 + 1] +
                      lds_x2p[tid * 4 + 2] + lds_x2p[tid * 4 + 3];
    __syncthreads();

    // A fragments: 4 row-tiles x 2 K-halves, loaded once, reused for all 16 col-tiles.
    // A-layout: lane holds A[m = lane&15][k = quad*8 + j]
    bf16x8 afrag[4][2];
    #pragma unroll
    for (int rt = 0; rt < 4; ++rt) {
        const int rg = row0 + rt * 16 + l15;
        #pragma unroll
        for (int kk = 0; kk < 2; ++kk) {
            const float4* p4 = (const float4*)(x + (size_t)rg * 64 + kk * 32 + quad * 8);
            float4 u0 = p4[0], u1 = p4[1];
            bf16x8 f;
            f[0] = (short)f2bf(u0.x); f[1] = (short)f2bf(u0.y);
            f[2] = (short)f2bf(u0.z); f[3] = (short)f2bf(u0.w);
            f[4] = (short)f2bf(u1.x); f[5] = (short)f2bf(u1.y);
            f[6] = (short)f2bf(u1.z); f[7] = (short)f2bf(u1.w);
            afrag[rt][kk] = f;
        }
    }

    // per-lane row constants: -BETA*||x_row||^2 ; C/D row = quad*4 + reg
    float pre[16];
    #pragma unroll
    for (int rt = 0; rt < 4; ++rt)
        #pragma unroll
        for (int reg = 0; reg < 4; ++reg)
            pre[rt * 4 + reg] = -BETA * lds_x2[rt * 16 + quad * 4 + reg];

    float op[16][3];
    #pragma unroll
    for (int v = 0; v < 16; ++v) { op[v][0] = 0.f; op[v][1] = 0.f; op[v][2] = 0.f; }

    const int colbase = wave * 256 + l15;
    for (int ct = 0; ct < 16; ++ct) {
        const int j = colbase + ct * 16;       // this lane's column (C/D col = lane&15)
        // B-layout: lane holds B[k = quad*8 + t][n = lane&15]; B[k][n] = centers[n][k]
        const unsigned short* cp = cbf + (size_t)j * 64 + quad * 8;
        bf16x8 b0 = *(const bf16x8*)cp;
        bf16x8 b1 = *(const bf16x8*)(cp + 32);

        f32x4 acc[4];
        #pragma unroll
        for (int rt = 0; rt < 4; ++rt) {
            f32x4 z = {0.f, 0.f, 0.f, 0.f};
            acc[rt] = __builtin_amdgcn_mfma_f32_16x16x32_bf16(afrag[rt][0], b0, z, 0, 0, 0);
            acc[rt] = __builtin_amdgcn_mfma_f32_16x16x32_bf16(afrag[rt][1], b1, acc[rt], 0, 0, 0);
        }

        const float c2t = -BETA * lds_c2[j];
        float arg[16], mx = -1e30f;
        #pragma unroll
        for (int rt = 0; rt < 4; ++rt)
            #pragma unroll
            for (int reg = 0; reg < 4; ++reg) {
                float a = fmaf(acc[rt][reg], 2.0f * BETA, pre[rt * 4 + reg] + c2t);
                arg[rt * 4 + reg] = a;
                mx = fmaxf(mx, a);
            }

        // exp(-35) * 1024 * |W|~0.02 ~ 1e-15 << 1.5e-2: safe to prune.
        if (__ballot(mx > -35.f) != 0ull) {
            float w0 = lds_W[0][j], w1 = lds_W[1][j], w2 = lds_W[2][j];
            #pragma unroll
            for (int v = 0; v < 16; ++v) {
                float e = __expf(arg[v]);
                op[v][0] = fmaf(e, w0, op[v][0]);
                op[v][1] = fmaf(e, w1, op[v][1]);
                op[v][2] = fmaf(e, w2, op[v][2]);
            }
        }
    }

    // reduce over the 16 columns (lanes sharing quad): butterfly on lane bits 0..3
    #pragma unroll
    for (int m = 1; m <= 8; m <<= 1)
        #pragma unroll
        for (int v = 0; v < 16; ++v)
            #pragma unroll
            for (int k = 0; k < 3; ++k)
                op[v][k] += __shfl_xor(op[v][k], m);

    if (l15 == 0) {
        #pragma unroll
        for (int rt = 0; rt < 4; ++rt)
            #pragma unroll
            for (int reg = 0; reg < 4; ++reg) {
                int r = rt * 16 + quad * 4 + reg;
                red[wave][r][0] = op[rt * 4 + reg][0];
                red[wave][r][1] = op[rt * 4 + reg][1];
                red[wave][r][2] = op[rt * 4 + reg][2];
            }
    }
    __syncthreads();

    // final: sum 4 waves + fp32 x @ W_x^T + b
    if (tid < 192) {
        int r = tid / 3, k = tid - r * 3;
        float s = red[0][r][k] + red[1][r][k] + red[2][r][k] + red[3][r][k];
        const float* xr = x + (size_t)(row0 + r) * 64;
        const float* wr = W + k * 1088;
        float dot = 0.f;
        #pragma unroll
        for (int c = 0; c < 64; ++c) dot = fmaf(xr[c], wr[c], dot);
        out[(size_t)(row0 + r) * 3 + k] = s + dot + b[k];
    }
}

extern "C" void kernel_launch(void* const* d_in, const int* in_sizes, int n_in,
                              void* d_out, int out_size, void* d_ws, size_t ws_size,
                              hipStream_t stream) {
    const float* x       = (const float*)d_in[0];
    const float* centers = (const float*)d_in[1];
    const float* W       = (const float*)d_in[2];
    const float* b       = (const float*)d_in[3];
    float* out = (float*)d_out;

    float* c2ws = (float*)d_ws;                                  // 1024 f32
    unsigned short* cbf = (unsigned short*)((char*)d_ws + 4096); // 1024x64 bf16

    const int n = in_sizes[0] / 64;

    rbfn_prep<<<1024, 64, 0, stream>>>(centers, cbf, c2ws);
    rbfn_main<<<n / 64, 256, 0, stream>>>(x, cbf, c2ws, W, b, out);
}

// Round 2
// 87.651 us; speedup vs baseline: 1.2671x; 1.2671x over previous
//
#include <hip/hip_runtime.h>
#include <hip/hip_bf16.h>
#include <math.h>

typedef short bf16x8 __attribute__((ext_vector_type(8)));
typedef float f32x4 __attribute__((ext_vector_type(4)));
typedef unsigned int uint32;

#define BETA 10.0f
#define PRUNE_THRESH -80.0f
// Certificate margin: bf16-trunc A + rtne B dot error |delta| <~ 2 abs -> 20*delta <~ 40.
// Skipping when computed bound <= -80 => true arg <= -40 => contribution
// <= exp(-40)*1024*0.02 ~ 9e-17 << 1.5e-2 threshold. Slow path handles the rest exactly.

__device__ __forceinline__ uint32 f2bf_rtne(float f) {
    uint32 u = __float_as_uint(f);
    u += 0x7FFFu + ((u >> 16) & 1u);
    return u >> 16;
}
__device__ __forceinline__ uint32 pk_rtne(float a, float b) {
    return f2bf_rtne(a) | (f2bf_rtne(b) << 16);
}
__device__ __forceinline__ uint32 pk_trunc(float a, float b) {
    return (__float_as_uint(a) >> 16) | (__float_as_uint(b) & 0xFFFF0000u);
}
__device__ __forceinline__ f32x4 vmax4(f32x4 a, f32x4 b) {
    f32x4 r;
    r[0] = fmaxf(a[0], b[0]); r[1] = fmaxf(a[1], b[1]);
    r[2] = fmaxf(a[2], b[2]); r[3] = fmaxf(a[3], b[3]);
    return r;
}

#define GLDS(g, l) __builtin_amdgcn_global_load_lds( \
    (const __attribute__((address_space(1))) unsigned int*)(g), \
    (__attribute__((address_space(3))) unsigned int*)(l), 16, 0, 0)

// Prep: centers -> bf16 (RTNE), chunk-swizzled layout so the LDS copy is
// bank-conflict-free at read time, plus c2m[j] = -BETA*||c_j||^2.
// Swizzle: 16-B chunk c (0..7) of column j stored at j*128 + ((c+j)&7)*16.
__global__ void rbfn_prep(const float* __restrict__ centers,
                          uint32* __restrict__ cbf,
                          float* __restrict__ c2m) {
    const int tid = threadIdx.x;
    const int j = blockIdx.x * 64 + (tid >> 2);  // center index
    const int seg = tid & 3;                     // 16-element segment
    const float4* cp = (const float4*)(centers + j * 64 + seg * 16);
    const float4 f0 = cp[0], f1 = cp[1], f2 = cp[2], f3 = cp[3];
    float s = f0.x*f0.x + f0.y*f0.y + f0.z*f0.z + f0.w*f0.w
            + f1.x*f1.x + f1.y*f1.y + f1.z*f1.z + f1.w*f1.w
            + f2.x*f2.x + f2.y*f2.y + f2.z*f2.z + f2.w*f2.w
            + f3.x*f3.x + f3.y*f3.y + f3.z*f3.z + f3.w*f3.w;
    uint4 p0, p1;
    p0.x = pk_rtne(f0.x, f0.y); p0.y = pk_rtne(f0.z, f0.w);
    p0.z = pk_rtne(f1.x, f1.y); p0.w = pk_rtne(f1.z, f1.w);
    p1.x = pk_rtne(f2.x, f2.y); p1.y = pk_rtne(f2.z, f2.w);
    p1.z = pk_rtne(f3.x, f3.y); p1.w = pk_rtne(f3.z, f3.w);
    const int c0 = seg * 2, c1 = seg * 2 + 1;
    char* base = (char*)cbf + j * 128;
    *(uint4*)(base + (((c0 + j) & 7) << 4)) = p0;
    *(uint4*)(base + (((c1 + j) & 7) << 4)) = p1;
    s += __shfl_xor(s, 1);
    s += __shfl_xor(s, 2);
    if (seg == 0) c2m[j] = -BETA * s;
}

struct AccPack { f32x4 a[8]; };

// Cold path: exact rbf contribution when the bound certificate fails (never
// fires with this data; kept for unconditional correctness).
__device__ __attribute__((noinline)) void rbfn_slow(
    AccPack ap, float* red, const float* x2p, const float* W,
    float c2ct, int j, int rbase, int quad) {
    #pragma unroll
    for (int rt = 0; rt < 8; ++rt) {
        #pragma unroll
        for (int rg = 0; rg < 4; ++rg) {
            const int r = rbase + rt * 16 + quad * 4 + rg;
            const float arg = fmaf(2.0f * BETA, ap.a[rt][rg], c2ct - BETA * x2p[r]);
            if (arg > PRUNE_THRESH) {
                const float e = expf(arg);
                atomicAdd(&red[r * 3 + 0], e * W[0 * 1088 + 64 + j]);
                atomicAdd(&red[r * 3 + 1], e * W[1 * 1088 + 64 + j]);
                atomicAdd(&red[r * 3 + 2], e * W[2 * 1088 + 64 + j]);
            }
        }
    }
}

// Block = 256 rows x 1024 centers. 512 threads = 8 waves: 2 rowgrps x 4 colgrps.
// All centers staged in LDS once (128 KB) -> 1 block/CU (LDS-capped, by design).
__global__ __launch_bounds__(512, 2) void rbfn_main(
    const float* __restrict__ x,
    const uint32* __restrict__ cbf,
    const float* __restrict__ c2m,
    const float* __restrict__ W,
    const float* __restrict__ bias,
    float* __restrict__ out)
{
    __shared__ __align__(16) char  lds_cbf[131072];
    __shared__ __align__(16) float lds_x2[256];
    __shared__ __align__(16) float red[768];   // seeded with x@Wx^T; rbf adds atomically

    const int tid = threadIdx.x;
    const int wv = tid >> 6;
    const int lane = tid & 63;
    const int quad = lane >> 4;
    const int l15 = lane & 15;
    const int rowgrp = wv >> 2;   // 0..1 -> 128 rows each
    const int colgrp = wv & 3;    // 0..3 -> 256 cols each
    const int row0 = blockIdx.x * 256;

    // 1. async stage swizzled centers into LDS (16 B/lane, wave-uniform dst base)
    {
        const char* g = (const char*)cbf + wv * 1024 + lane * 16;
        char* l = lds_cbf + wv * 1024;
        #pragma unroll
        for (int it = 0; it < 16; ++it)
            GLDS(g + it * 8192, l + it * 8192);
    }

    // 2. Wx segment weights (seg = tid&15 fixed across passes)
    const int seg = tid & 15;
    const float4 w0 = *(const float4*)(W + 0 * 1088 + seg * 4);
    const float4 w1 = *(const float4*)(W + 1 * 1088 + seg * 4);
    const float4 w2 = *(const float4*)(W + 2 * 1088 + seg * 4);

    // 3. single coalesced x pass: ||x||^2 and the exact fp32 x@Wx^T seed
    const float4* x4 = (const float4*)x;
    #pragma unroll
    for (int p = 0; p < 8; ++p) {
        const int chunk = p * 512 + tid;               // 0..4095 = 256 rows x 16 segs
        const float4 v = x4[(size_t)row0 * 16 + chunk];
        float s2 = v.x * v.x + v.y * v.y + v.z * v.z + v.w * v.w;
        float d0 = v.x * w0.x + v.y * w0.y + v.z * w0.z + v.w * w0.w;
        float d1 = v.x * w1.x + v.y * w1.y + v.z * w1.z + v.w * w1.w;
        float d2 = v.x * w2.x + v.y * w2.y + v.z * w2.z + v.w * w2.w;
        #pragma unroll
        for (int m = 1; m <= 8; m <<= 1) {
            s2 += __shfl_xor(s2, m);
            d0 += __shfl_xor(d0, m);
            d1 += __shfl_xor(d1, m);
            d2 += __shfl_xor(d2, m);
        }
        if (seg == 0) {
            const int r = chunk >> 4;
            lds_x2[r] = s2;
            red[r * 3 + 0] = d0;
            red[r * 3 + 1] = d1;
            red[r * 3 + 2] = d2;
        }
    }

    // 4. A fragments (trunc-rounded bf16; precision covered by certificate margin)
    bf16x8 af[8][2];
    #pragma unroll
    for (int rt = 0; rt < 8; ++rt) {
        const float4* px = (const float4*)(x + (size_t)(row0 + rowgrp * 128 + rt * 16 + l15) * 64) + quad * 2;
        #pragma unroll
        for (int kk = 0; kk < 2; ++kk) {
            const float4 u0 = px[kk * 8];
            const float4 u1 = px[kk * 8 + 1];
            union { bf16x8 v; uint4 u; } t;
            t.u.x = pk_trunc(u0.x, u0.y);
            t.u.y = pk_trunc(u0.z, u0.w);
            t.u.z = pk_trunc(u1.x, u1.y);
            t.u.w = pk_trunc(u1.z, u1.w);
            af[rt][kk] = t.v;
        }
    }

    // 5. per-lane column constants (-BETA*||c_j||^2), kept in registers
    float c2r[16];
    const int jb = colgrp * 256 + l15;
    #pragma unroll
    for (int ct = 0; ct < 16; ++ct)
        c2r[ct] = c2m[jb + ct * 16];

    __syncthreads();

    // 6. pm = max over this lane's 32 rows of (-BETA*||x||^2)
    float mn = 1e30f;
    #pragma unroll
    for (int rt = 0; rt < 8; ++rt) {
        const float4 q = *(const float4*)&lds_x2[rowgrp * 128 + rt * 16 + quad * 4];
        mn = fminf(mn, fminf(fminf(q.x, q.y), fminf(q.z, q.w)));
    }
    const float pm = -BETA * mn;

    // 7. main loop: 16 col-tiles, B from LDS (prefetch depth 1), bound certificate
    const char* cb = lds_cbf;
    const int base0 = jb * 128 + (((quad + jb) & 7) << 4);       // kk=0 chunk (swizzle ct-invariant)
    const int base1 = jb * 128 + (((quad + 4 + jb) & 7) << 4);   // kk=1 chunk
    bf16x8 b0 = *(const bf16x8*)(cb + base0);
    bf16x8 b1 = *(const bf16x8*)(cb + base1);
    #pragma unroll
    for (int ct = 0; ct < 16; ++ct) {
        bf16x8 nb0 = b0, nb1 = b1;
        if (ct < 15) {
            nb0 = *(const bf16x8*)(cb + base0 + (ct + 1) * 2048);
            nb1 = *(const bf16x8*)(cb + base1 + (ct + 1) * 2048);
        }
        f32x4 acc[8];
        #pragma unroll
        for (int rt = 0; rt < 8; ++rt) {
            const f32x4 z = {0.f, 0.f, 0.f, 0.f};
            acc[rt] = __builtin_amdgcn_mfma_f32_16x16x32_bf16(af[rt][0], b0, z, 0, 0, 0);
            acc[rt] = __builtin_amdgcn_mfma_f32_16x16x32_bf16(af[rt][1], b1, acc[rt], 0, 0, 0);
        }
        f32x4 m0 = vmax4(acc[0], acc[1]);
        f32x4 m1 = vmax4(acc[2], acc[3]);
        f32x4 m2 = vmax4(acc[4], acc[5]);
        f32x4 m3 = vmax4(acc[6], acc[7]);
        m0 = vmax4(m0, m1);
        m2 = vmax4(m2, m3);
        m0 = vmax4(m0, m2);
        const float mx = fmaxf(fmaxf(m0[0], m0[1]), fmaxf(m0[2], m0[3]));
        const float bound = fmaf(2.0f * BETA, mx, pm + c2r[ct]);
        if (__builtin_expect(__ballot(bound > PRUNE_THRESH) != 0ull, 0)) {
            AccPack ap;
            #pragma unroll
            for (int rt = 0; rt < 8; ++rt) ap.a[rt] = acc[rt];
            rbfn_slow(ap, red, lds_x2, W, c2r[ct], jb + ct * 16, rowgrp * 128, quad);
        }
        b0 = nb0; b1 = nb1;
    }

    __syncthreads();

    // 8. epilogue: out = red + bias, vectorized float4 stores
    if (tid < 192) {
        const float4 rv = *((const float4*)red + tid);
        float4 o;
        o.x = rv.x + bias[(tid + 0) % 3];
        o.y = rv.y + bias[(tid + 1) % 3];
        o.z = rv.z + bias[(tid + 2) % 3];
        o.w = rv.w + bias[(tid + 3) % 3];
        ((float4*)out)[blockIdx.x * 192 + tid] = o;
    }
}

extern "C" void kernel_launch(void* const* d_in, const int* in_sizes, int n_in,
                              void* d_out, int out_size, void* d_ws, size_t ws_size,
                              hipStream_t stream) {
    const float* x       = (const float*)d_in[0];
    const float* centers = (const float*)d_in[1];
    const float* W       = (const float*)d_in[2];
    const float* b       = (const float*)d_in[3];
    float* out = (float*)d_out;

    float*  c2m = (float*)d_ws;                         // 4 KB
    uint32* cbf = (uint32*)((char*)d_ws + 4096);        // 128 KB, swizzled bf16

    const int n = in_sizes[0] / 64;                     // 65536

    rbfn_prep<<<16, 256, 0, stream>>>(centers, cbf, c2m);
    rbfn_main<<<n / 256, 512, 0, stream>>>(x, cbf, c2m, W, b, out);
}